// Round 1
// baseline (434.866 us; speedup 1.0000x reference)
//
#include <hip/hip_runtime.h>

#define DM 1024
#define NH 16
#define HD 64
#define BATCH 2
#define SEQ 2048
#define MROWS (BATCH*SEQ)   // 4096

typedef unsigned short u16;
typedef __bf16 bf16x8 __attribute__((ext_vector_type(8)));
typedef float f32x4 __attribute__((ext_vector_type(4)));
typedef unsigned int u32x4 __attribute__((ext_vector_type(4)));

__device__ __forceinline__ u16 f2bf(float f) {
  unsigned u = __builtin_bit_cast(unsigned, f);
  u += 0x7fffu + ((u >> 16) & 1u);
  return (u16)(u >> 16);
}
__device__ __forceinline__ float bf2f(u16 h) {
  return __builtin_bit_cast(float, ((unsigned)h) << 16);
}
__device__ __forceinline__ bf16x8 ld8(const u16* p) {
  return __builtin_bit_cast(bf16x8, *reinterpret_cast<const u32x4*>(p));
}

// ---------- fp32 -> bf16 conversion ----------
__global__ void conv_kernel(const float* __restrict__ in, u16* __restrict__ out, int n) {
  int i = (blockIdx.x * 256 + threadIdx.x) * 4;
  if (i >= n) return;
  f32x4 v = *reinterpret_cast<const f32x4*>(in + i);
  out[i + 0] = f2bf(v[0]);
  out[i + 1] = f2bf(v[1]);
  out[i + 2] = f2bf(v[2]);
  out[i + 3] = f2bf(v[3]);
}

// ---------- RoPE cos/sin table: tab[s*64 + i] = cos, tab[s*64 + 32 + i] = sin ----------
__global__ void tab_kernel(float* __restrict__ tab) {
  int t = blockIdx.x * 256 + threadIdx.x;
  if (t >= SEQ * 32) return;
  int s = t >> 5, i = t & 31;
  float inv = powf(10000.0f, -(float)i / 32.0f);
  float f = (float)s * inv;
  tab[s * 64 + i] = cosf(f);
  tab[s * 64 + 32 + i] = sinf(f);
}

// ---------- GEMM: C[m,n] = sum_k A[m,k] * B[n,k]   (A,B bf16 row-major) ----------
// MODE 0: store bf16 C
// MODE 1: store f32 C + bf16 C
// MODE 2: gate epilogue: Cf[idx] = mult[idx] * sigmoid(acc + bias[col])
template <int MODE>
__global__ __launch_bounds__(256) void gemm_bt(
    const u16* __restrict__ A, const u16* __restrict__ B,
    u16* __restrict__ Cbf, float* __restrict__ Cf,
    const float* __restrict__ bias, const float* __restrict__ mult,
    int M, int N, int K, size_t bz, size_t cz) {
  B += blockIdx.z * bz;
  u16* Cb = Cbf + blockIdx.z * cz;
  const int m0 = blockIdx.y * 64, n0 = blockIdx.x * 64;
  const int t = threadIdx.x;
  const int w = t >> 6, l = t & 63;
  const int wr = w >> 1, wc = w & 1;
  const int lr = l & 15, lg = l >> 4;
  __shared__ __align__(16) u16 As[64][32];
  __shared__ __align__(16) u16 Bs[64][32];
  f32x4 acc[2][2] = {};
  const int srow = t >> 2, scol = (t & 3) << 3;
  for (int kt = 0; kt < K; kt += 32) {
    *reinterpret_cast<u32x4*>(&As[srow][scol]) =
        *reinterpret_cast<const u32x4*>(&A[(size_t)(m0 + srow) * K + kt + scol]);
    *reinterpret_cast<u32x4*>(&Bs[srow][scol]) =
        *reinterpret_cast<const u32x4*>(&B[(size_t)(n0 + srow) * K + kt + scol]);
    __syncthreads();
    bf16x8 af[2], bfr[2];
    af[0] = ld8(&As[wr * 32 + lr][lg * 8]);
    af[1] = ld8(&As[wr * 32 + 16 + lr][lg * 8]);
    bfr[0] = ld8(&Bs[wc * 32 + lr][lg * 8]);
    bfr[1] = ld8(&Bs[wc * 32 + 16 + lr][lg * 8]);
#pragma unroll
    for (int mi = 0; mi < 2; ++mi)
#pragma unroll
      for (int ni = 0; ni < 2; ++ni)
        acc[mi][ni] = __builtin_amdgcn_mfma_f32_16x16x32_bf16(af[mi], bfr[ni], acc[mi][ni], 0, 0, 0);
    __syncthreads();
  }
#pragma unroll
  for (int mi = 0; mi < 2; ++mi)
#pragma unroll
    for (int ni = 0; ni < 2; ++ni)
#pragma unroll
      for (int r = 0; r < 4; ++r) {
        int row = m0 + wr * 32 + mi * 16 + lg * 4 + r;
        int col = n0 + wc * 32 + ni * 16 + lr;
        size_t idx = (size_t)row * N + col;
        float v = acc[mi][ni][r];
        if constexpr (MODE == 0) {
          Cb[idx] = f2bf(v);
        } else if constexpr (MODE == 1) {
          Cf[idx] = v;
          Cb[idx] = f2bf(v);
        } else {
          float g = 1.0f / (1.0f + __expf(-(v + bias[col])));
          Cf[idx] = mult[idx] * g;
        }
      }
}

// ---------- RoPE + layout transform: [B][S][H*64] -> [B*H][S][64] ----------
__global__ void rope_kernel(const u16* __restrict__ Qin, const u16* __restrict__ Kin,
                            const u16* __restrict__ Vin, u16* __restrict__ Qr,
                            u16* __restrict__ Kr, u16* __restrict__ Vr,
                            const float* __restrict__ tab) {
  int t = blockIdx.x * 256 + threadIdx.x;
  int i = t & 31;
  int s = (t >> 5) & (SEQ - 1);
  int bh = t >> 16;  // t / (SEQ*32) = t / 65536
  if (bh >= BATCH * NH) return;
  int b = bh >> 4, h = bh & 15;
  size_t ib = ((size_t)(b * SEQ + s)) * DM + h * 64;
  size_t ob = ((size_t)bh * SEQ + s) * 64;
  float c = tab[s * 64 + i], sn = tab[s * 64 + 32 + i];
  float q1 = bf2f(Qin[ib + i]), q2 = bf2f(Qin[ib + 32 + i]);
  float k1 = bf2f(Kin[ib + i]), k2 = bf2f(Kin[ib + 32 + i]);
  Qr[ob + i] = f2bf(q1 * c - q2 * sn);
  Qr[ob + 32 + i] = f2bf(q2 * c + q1 * sn);
  Kr[ob + i] = f2bf(k1 * c - k2 * sn);
  Kr[ob + 32 + i] = f2bf(k2 * c + k1 * sn);
  Vr[ob + i] = Vin[ib + i];
  Vr[ob + 32 + i] = Vin[ib + 32 + i];
}

// ---------- flash attention: 1 wave / block, 16 q-rows, KV tiles of 32 ----------
__global__ __launch_bounds__(64) void attn_kernel(
    const u16* __restrict__ Q, const u16* __restrict__ Kt, const u16* __restrict__ V,
    u16* __restrict__ O) {
  const int qb = blockIdx.x;
  const int bh = blockIdx.y;
  const int l = threadIdx.x;
  const int lr = l & 15, lg = l >> 4;
  const int q0 = qb * 16;
  const size_t base = (size_t)bh * SEQ * 64;
  __shared__ __align__(16) u16 Ps[16][32];
  __shared__ __align__(16) u16 Vs[32][64];

  bf16x8 qf[2];
  qf[0] = ld8(&Q[base + (size_t)(q0 + lr) * 64 + lg * 8]);
  qf[1] = ld8(&Q[base + (size_t)(q0 + lr) * 64 + 32 + lg * 8]);

  f32x4 oacc[4] = {};
  float m_s[4], l_s[4];
#pragma unroll
  for (int r = 0; r < 4; ++r) { m_s[r] = -1e30f; l_s[r] = 0.0f; }

  const int ntiles = (q0 + 15) / 32 + 1;
  for (int tk = 0; tk < ntiles; ++tk) {
    const int kv0 = tk * 32;
    // scores: two 16-col halves
    f32x4 s[2];
#pragma unroll
    for (int hh = 0; hh < 2; ++hh) {
      bf16x8 kf0 = ld8(&Kt[base + (size_t)(kv0 + hh * 16 + lr) * 64 + lg * 8]);
      bf16x8 kf1 = ld8(&Kt[base + (size_t)(kv0 + hh * 16 + lr) * 64 + 32 + lg * 8]);
      f32x4 z = {};
      z = __builtin_amdgcn_mfma_f32_16x16x32_bf16(qf[0], kf0, z, 0, 0, 0);
      z = __builtin_amdgcn_mfma_f32_16x16x32_bf16(qf[1], kf1, z, 0, 0, 0);
      s[hh] = z;
    }
    // stage V tile (32 x 64)
#pragma unroll
    for (int i = 0; i < 4; ++i) {
      int flat = i * 512 + l * 8;
      int row = flat >> 6, col = flat & 63;
      *reinterpret_cast<u32x4*>(&Vs[row][col]) =
          *reinterpret_cast<const u32x4*>(&V[base + (size_t)(kv0 + row) * 64 + col]);
    }
    // online softmax (per lane handles 4 rows)
    float scale_prev[4];
#pragma unroll
    for (int r = 0; r < 4; ++r) {
      int qg = q0 + lg * 4 + r;
      float v0 = s[0][r] * 0.125f;
      float v1 = s[1][r] * 0.125f;
      if (kv0 + lr > qg) v0 = -1e30f;
      if (kv0 + 16 + lr > qg) v1 = -1e30f;
      float mt = fmaxf(v0, v1);
#pragma unroll
      for (int mm = 1; mm < 16; mm <<= 1) mt = fmaxf(mt, __shfl_xor(mt, mm));
      float mn = fmaxf(m_s[r], mt);
      float p0 = __expf(v0 - mn);
      float p1 = __expf(v1 - mn);
      float ps = p0 + p1;
#pragma unroll
      for (int mm = 1; mm < 16; mm <<= 1) ps += __shfl_xor(ps, mm);
      scale_prev[r] = __expf(m_s[r] - mn);
      l_s[r] = l_s[r] * scale_prev[r] + ps;
      m_s[r] = mn;
      Ps[lg * 4 + r][lr] = f2bf(p0);
      Ps[lg * 4 + r][16 + lr] = f2bf(p1);
    }
    // rescale output accumulators
#pragma unroll
    for (int dc = 0; dc < 4; ++dc)
#pragma unroll
      for (int r = 0; r < 4; ++r) oacc[dc][r] *= scale_prev[r];
    __syncthreads();
    // PV: out[q][d] += P[q][kv] * V[kv][d]
    bf16x8 pf = ld8(&Ps[lr][lg * 8]);
#pragma unroll
    for (int dc = 0; dc < 4; ++dc) {
      union { bf16x8 v; u16 s[8]; } uv;
#pragma unroll
      for (int j = 0; j < 8; ++j) uv.s[j] = Vs[lg * 8 + j][dc * 16 + lr];
      oacc[dc] = __builtin_amdgcn_mfma_f32_16x16x32_bf16(pf, uv.v, oacc[dc], 0, 0, 0);
    }
    __syncthreads();
  }
  // epilogue: normalize + store to [B][S][H*64]
  const int b = bh >> 4, h = bh & 15;
#pragma unroll
  for (int dc = 0; dc < 4; ++dc)
#pragma unroll
    for (int r = 0; r < 4; ++r) {
      int qg = q0 + lg * 4 + r;
      float val = oacc[dc][r] / l_s[r];
      O[((size_t)(b * SEQ + qg)) * DM + h * 64 + dc * 16 + lr] = f2bf(val);
    }
}

extern "C" void kernel_launch(void* const* d_in, const int* in_sizes, int n_in,
                              void* d_out, int out_size, void* d_ws, size_t ws_size,
                              hipStream_t stream) {
  const float* x = (const float*)d_in[0];
  const float* Wq = (const float*)d_in[1];
  const float* Wk = (const float*)d_in[2];
  const float* Wv = (const float*)d_in[3];
  const float* Wo = (const float*)d_in[4];
  const float* Wg = (const float*)d_in[5];
  const float* bg = (const float*)d_in[6];
  float* out = (float*)d_out;

  const size_t NX = (size_t)MROWS * DM;  // 4M
  const size_t NW = (size_t)DM * DM;     // 1M
  u16* xbf = (u16*)d_ws;
  u16* wbf = xbf + NX;            // 5 weights
  u16* qkv = wbf + 5 * NW;        // Q,K,V  [B][S][DM], each NX
  u16* qkvr = qkv + 3 * NX;       // Qr,Kr,Vr [BH][S][64], each NX
  u16* attn = qkvr + 3 * NX;      // NX
  u16* outbf = attn + NX;         // NX
  float* outf = (float*)(outbf + NX);
  float* tab = outf + NX;

  // 1. conversions
  conv_kernel<<<NX / 1024, 256, 0, stream>>>(x, xbf, (int)NX);
  conv_kernel<<<NW / 1024, 256, 0, stream>>>(Wq, wbf + 0 * NW, (int)NW);
  conv_kernel<<<NW / 1024, 256, 0, stream>>>(Wk, wbf + 1 * NW, (int)NW);
  conv_kernel<<<NW / 1024, 256, 0, stream>>>(Wv, wbf + 2 * NW, (int)NW);
  conv_kernel<<<NW / 1024, 256, 0, stream>>>(Wo, wbf + 3 * NW, (int)NW);
  conv_kernel<<<NW / 1024, 256, 0, stream>>>(Wg, wbf + 4 * NW, (int)NW);
  // 2. rope table
  tab_kernel<<<(SEQ * 32) / 256, 256, 0, stream>>>(tab);
  // 3. QKV projections
  gemm_bt<0><<<dim3(DM / 64, MROWS / 64, 3), 256, 0, stream>>>(
      xbf, wbf, qkv, nullptr, nullptr, nullptr, MROWS, DM, DM, NW, NX);
  // 4. RoPE + transpose
  rope_kernel<<<(BATCH * NH * SEQ * 32) / 256, 256, 0, stream>>>(
      qkv, qkv + NX, qkv + 2 * NX, qkvr, qkvr + NX, qkvr + 2 * NX, tab);
  // 5. attention
  attn_kernel<<<dim3(SEQ / 16, BATCH * NH), 64, 0, stream>>>(
      qkvr, qkvr + NX, qkvr + 2 * NX, attn);
  // 6. output projection
  gemm_bt<1><<<dim3(DM / 64, MROWS / 64, 1), 256, 0, stream>>>(
      attn, wbf + 3 * NW, outbf, outf, nullptr, nullptr, MROWS, DM, DM, 0, 0);
  // 7. gate + final
  gemm_bt<2><<<dim3(DM / 64, MROWS / 64, 1), 256, 0, stream>>>(
      outbf, wbf + 4 * NW, nullptr, out, bg, outf, MROWS, DM, DM, 0, 0);
}